// Round 17
// baseline (57.194 us; speedup 1.0000x reference)
//
#include <hip/hip_runtime.h>
#include <hip/hip_bf16.h>
#include <stdint.h>

typedef __attribute__((ext_vector_type(4))) float f32x4;
typedef __attribute__((ext_vector_type(8))) short bf16x8;

#define NCH 21
#define NROW 256
#define DIM 4096
#define BK 64
#define NTILE 10  // upper-triangle 64x64 tiles of the 256x256 Gram

__device__ const int g_TI[NTILE] = {0, 0, 0, 0, 1, 1, 1, 2, 2, 3};
__device__ const int g_TJ[NTILE] = {0, 1, 2, 3, 1, 2, 3, 2, 3, 3};

__device__ __forceinline__ uint32_t pack_bf2(float x, float y) {
  __hip_bfloat162 h = __float22bfloat162_rn(float2{x, y});  // v_cvt_pk_bf16_f32
  union { __hip_bfloat162 h; uint32_t u; } c;
  c.h = h;
  return c.u;
}

// ---------------------------------------------------------------------------
// R14/R16 structure with GENERALIZED K-split P (non-power-of-2): one
// 1024-thread block per (ch,ks), grid = NCH*P. P=12 -> 252 blocks ~= one per
// CU on 98% of the chip (R16's P=8 left 88 CUs idle; per-CU streaming rate
// ~12.3 GB/s was the invariant, so aggregate = active CUs x rate).
// Block (ch,ks) owns BK-steps [ks*64/P, (ks+1)*64/P) -- 5 or 6 iters.
// Everything else identical: stage full 256x64 slab once per iter (zero
// redundancy), 10 waves compute the 10 upper-tri tiles, XOR-swizzled bf16
// LDS, reg-prefetch one iter ahead, 2 barriers/iter.
// ---------------------------------------------------------------------------
__global__ __launch_bounds__(1024, 4) void gram_kernel(
    const float* __restrict__ src, const float* __restrict__ tgt,
    float* __restrict__ Gp, int P) {
  const int g = blockIdx.x;
  const int ch = g / P;
  const int ks = g - ch * P;
  const int step0 = (ks * (DIM / BK)) / P;        // inclusive
  const int step1 = ((ks + 1) * (DIM / BK)) / P;  // exclusive
  const int kbase = step0 * BK;
  const int nk = step1 - step0;                   // 5 or 6 at P=12
  const int tid = threadIdx.x;
  const int lane = tid & 63;
  const int wave = tid >> 6;             // 0..15

  __shared__ __attribute__((aligned(16))) ushort S[256 * 64];  // 32 KB bf16 slab

  f32x4 acc[4][4];
#pragma unroll
  for (int m = 0; m < 4; ++m)
#pragma unroll
    for (int n = 0; n < 4; ++n)
      acc[m][n] = (f32x4){0.f, 0.f, 0.f, 0.f};

  // staging geometry: 256 rows x 64 f32 = 4096 16B-chunks; thread handles
  // chunk ids tid, tid+1024, tid+2048, tid+3072 (wave reads 1KB contiguous).
  const float* gptr[4];
  int lw[4];
#pragma unroll
  for (int i = 0; i < 4; ++i) {
    const int id = i * 1024 + tid;
    const int row = id >> 4;             // 0..255
    const int c16 = id & 15;             // f32 chunk within row
    const float* base = (row < 128) ? src + ((size_t)row * NCH + ch) * DIM
                                    : tgt + ((size_t)(row - 128) * NCH + ch) * DIM;
    gptr[i] = base + kbase + c16 * 4;
    const int sch = (c16 >> 1) ^ (row & 7);     // swizzled 16B bf16 chunk
    lw[i] = row * 64 + sch * 8 + (c16 & 1) * 4; // ushort index (8B half-chunk)
  }

  const int ti = g_TI[wave < NTILE ? wave : 0];
  const int tj = g_TJ[wave < NTILE ? wave : 0];

  // prefetch slab 0
  f32x4 v[4];
#pragma unroll
  for (int i = 0; i < 4; ++i) v[i] = *reinterpret_cast<const f32x4*>(gptr[i]);

  for (int it = 0; it < nk; ++it) {
    __syncthreads();  // previous iteration's LDS reads done
    // stage regs -> LDS (cvt_pk, swizzled, conflict-free)
#pragma unroll
    for (int i = 0; i < 4; ++i) {
      uint2 wv;
      wv.x = pack_bf2(v[i].x, v[i].y);
      wv.y = pack_bf2(v[i].z, v[i].w);
      *reinterpret_cast<uint2*>(&S[lw[i]]) = wv;
    }
    // issue next slab's loads; they fly across the MFMA phase
    if (it + 1 < nk) {
      const int ko = (it + 1) * BK;
#pragma unroll
      for (int i = 0; i < 4; ++i)
        v[i] = *reinterpret_cast<const f32x4*>(gptr[i] + ko);
    }
    asm volatile("s_waitcnt lgkmcnt(0)" ::: "memory");  // ds_writes visible
    __builtin_amdgcn_s_barrier();
    asm volatile("" ::: "memory");

    if (wave < NTILE) {
#pragma unroll
      for (int kk = 0; kk < 2; ++kk) {
        const int chunk = kk * 4 + (lane >> 4);  // 16B bf16 chunk 0..7
        bf16x8 a[4], b[4];
#pragma unroll
        for (int m = 0; m < 4; ++m) {
          const int row = ti * 64 + m * 16 + (lane & 15);
          a[m] = *reinterpret_cast<const bf16x8*>(
              &S[row * 64 + ((chunk ^ (row & 7)) << 3)]);
        }
#pragma unroll
        for (int n = 0; n < 4; ++n) {
          const int row = tj * 64 + n * 16 + (lane & 15);
          b[n] = *reinterpret_cast<const bf16x8*>(
              &S[row * 64 + ((chunk ^ (row & 7)) << 3)]);
        }
#pragma unroll
        for (int m = 0; m < 4; ++m)
#pragma unroll
          for (int n = 0; n < 4; ++n)
            acc[m][n] = __builtin_amdgcn_mfma_f32_16x16x32_bf16(a[m], b[n],
                                                                acc[m][n], 0, 0, 0);
      }
    }
  }

  // C/D layout (m89): col = lane&15, row = (lane>>4)*4 + reg.
  if (wave < NTILE) {
    float* gp = Gp + (size_t)(ch * P + ks) * (NROW * NROW);
#pragma unroll
    for (int m = 0; m < 4; ++m)
#pragma unroll
      for (int n = 0; n < 4; ++n) {
        const int grow = ti * 64 + m * 16 + ((lane >> 4) << 2);
        const int gcol = tj * 64 + n * 16 + (lane & 15);
#pragma unroll
        for (int j = 0; j < 4; ++j)
          gp[(size_t)(grow + j) * NROW + gcol] = acc[m][n][j];
      }
  }
}

// ---------------------------------------------------------------------------
__device__ __forceinline__ float block_sum256(float v, float* sm) {
#pragma unroll
  for (int o = 32; o > 0; o >>= 1) v += __shfl_down(v, o, 64);
  const int lane = threadIdx.x & 63;
  const int wv = threadIdx.x >> 6;
  if (lane == 0) sm[wv] = v;
  __syncthreads();
  float r = 0.f;
  if (threadIdx.x == 0) r = sm[0] + sm[1] + sm[2] + sm[3];
  __syncthreads();
  return r;  // valid on thread 0
}

// ---------------------------------------------------------------------------
// Fold K-split partials for one (ch,tile) AND produce tile sum + diag trace.
__global__ __launch_bounds__(256) void foldsum_kernel(
    const f32x4* __restrict__ Gp, f32x4* __restrict__ Gf,
    float* __restrict__ sums, int P) {
  const int t = blockIdx.x;
  const int ch = blockIdx.y;
  const int ti = g_TI[t], tj = g_TJ[t];
  const bool isdiag = (ti == tj);
  const int tid = threadIdx.x;
  float s = 0.f, tr = 0.f;
#pragma unroll
  for (int i = 0; i < 4; ++i) {
    const int idx4 = tid * 4 + i;
    const int rrow = idx4 >> 4;       // 0..63
    const int c4 = idx4 & 15;         // 0..15
    const int base_v = (ti * 64 + rrow) * 64 + tj * 16 + c4;
    f32x4 v = Gp[(size_t)(ch * P) * 16384 + base_v];
    for (int p = 1; p < P; ++p) v += Gp[(size_t)(ch * P + p) * 16384 + base_v];
    Gf[(size_t)ch * 16384 + base_v] = v;
    s += (v.x + v.y) + (v.z + v.w);
    if (isdiag) {
      const int cb = c4 * 4;
#pragma unroll
      for (int e = 0; e < 4; ++e)
        if (cb + e == rrow) tr += v[e];
    }
  }
  __shared__ float sm[4];
  float sG = block_sum256(s, sm);
  float sT = block_sum256(tr, sm);
  if (tid == 0) {
    sums[ch * 20 + t] = sG;
    if (isdiag) sums[ch * 20 + 10 + ti] = sT;
  }
}

// ---------------------------------------------------------------------------
// per (tile, ch): w * sign * sum over tile of sum_a exp(-L2/(bw*2^a)).
__global__ __launch_bounds__(256) void mmd_kernel(const float* __restrict__ Gf,
                                                  const float* __restrict__ sums,
                                                  float* __restrict__ partial) {
  const int t = blockIdx.x;
  const int ch = blockIdx.y;
  const int ti = g_TI[t], tj = g_TJ[t];
  const int tid = threadIdx.x;
  const float* gg = Gf + (size_t)ch * (NROW * NROW);

  const float* sc = sums + ch * 20;
  float sumG = 0.f;
#pragma unroll
  for (int k = 0; k < NTILE; ++k)
    sumG += (g_TI[k] == g_TJ[k] ? 1.f : 2.f) * sc[k];
  const float trace = (sc[10] + sc[11]) + (sc[12] + sc[13]);
  const float sumL2 = 2.f * NROW * trace - 2.f * sumG;
  const float bw = sumL2 / (float)(NROW * NROW - NROW) * 0.25f;
  float inv[5];
#pragma unroll
  for (int a = 0; a < 5; ++a) inv[a] = -1.f / (bw * (float)(1 << a));

  __shared__ float dA[64], dB[64];
  if (tid < 64) dA[tid] = gg[(size_t)(ti * 64 + tid) * (NROW + 1)];
  else if (tid < 128) dB[tid - 64] = gg[(size_t)(tj * 64 + (tid - 64)) * (NROW + 1)];
  __syncthreads();

  const int col = tid & 63;
  const int qq = tid >> 6;
  const float dj = dB[col];
  float acc = 0.f;
#pragma unroll 4
  for (int it = 0; it < 16; ++it) {
    const int r = it * 4 + qq;
    const float L2 = dA[r] + dj - 2.f * gg[(size_t)(ti * 64 + r) * NROW + tj * 64 + col];
    float kv = 0.f;
#pragma unroll
    for (int a = 0; a < 5; ++a) kv += __expf(L2 * inv[a]);
    acc += kv;
  }
  __shared__ float sm[4];
  float tot = block_sum256(acc, sm);
  if (tid == 0) {
    float wgt = (ti == tj) ? 1.f : 2.f;                  // off-diag mirror
    float sgn = ((ti >= 2) == (tj >= 2)) ? 1.f : -1.f;   // XX/YY + , XY/YX -
    partial[ch * NTILE + t] = tot * wgt * sgn;
  }
}

__global__ __launch_bounds__(256) void final_kernel(const float* __restrict__ partial,
                                                    float* __restrict__ out) {
  const int tid = threadIdx.x;
  float v = (tid < NCH * NTILE) ? partial[tid] : 0.f;
  __shared__ float sm[4];
  float tot = block_sum256(v, sm);
  if (tid == 0) out[0] = tot * (1.f / (NCH * 128.f * 128.f));
}

// ---------------------------------------------------------------------------
extern "C" void kernel_launch(void* const* d_in, const int* in_sizes, int n_in,
                              void* d_out, int out_size, void* d_ws, size_t ws_size,
                              hipStream_t stream) {
  const float* src = (const float*)d_in[0];
  const float* tgt = (const float*)d_in[1];
  float* out = (float*)d_out;
  const size_t GSZ = (size_t)NROW * NROW;  // 65536

  // P=12 -> grid 252 ~= 1 block/CU on 98% of CUs (P=8 left 34% idle).
  // Ladder by workspace; P=16 excluded (R10: foldsum read 107MB = 44us).
  int P = 1;
  if (ws_size >= (NCH * 13 * GSZ + 512) * sizeof(float)) P = 12;
  else if (ws_size >= (NCH * 9 * GSZ + 512) * sizeof(float)) P = 8;
  else if (ws_size >= (NCH * 5 * GSZ + 512) * sizeof(float)) P = 4;
  else if (ws_size >= (NCH * 3 * GSZ + 512) * sizeof(float)) P = 2;

  float* Gp = (float*)d_ws;
  float* Gf = (P > 1) ? Gp + (size_t)NCH * P * GSZ : Gp;  // P==1: alias
  float* sums = Gf + (size_t)NCH * GSZ;                   // NCH*20
  float* partial = sums + NCH * 20;                       // NCH*10

  gram_kernel<<<dim3(NCH * P), 1024, 0, stream>>>(src, tgt, Gp, P);
  foldsum_kernel<<<dim3(NTILE, NCH), 256, 0, stream>>>((const f32x4*)Gp,
                                                       (f32x4*)Gf, sums, P);
  mmd_kernel<<<dim3(NTILE, NCH), 256, 0, stream>>>(Gf, sums, partial);
  final_kernel<<<1, 256, 0, stream>>>(partial, out);
}

// Round 18
// 43.880 us; speedup vs baseline: 1.3034x; 1.3034x over previous
//
#include <hip/hip_runtime.h>
#include <hip/hip_bf16.h>
#include <stdint.h>

typedef __attribute__((ext_vector_type(4))) float f32x4;
typedef __attribute__((ext_vector_type(8))) short bf16x8;

#define NCH 21
#define NROW 256
#define DIM 4096
#define BK 64
#define NTILE 10  // upper-triangle 64x64 tiles of the 256x256 Gram

__device__ const int g_TI[NTILE] = {0, 0, 0, 0, 1, 1, 1, 2, 2, 3};
__device__ const int g_TJ[NTILE] = {0, 1, 2, 3, 1, 2, 3, 2, 3, 3};

__device__ __forceinline__ uint32_t pack_bf2(float x, float y) {
  __hip_bfloat162 h = __float22bfloat162_rn(float2{x, y});  // v_cvt_pk_bf16_f32
  union { __hip_bfloat162 h; uint32_t u; } c;
  c.h = h;
  return c.u;
}

// ---------------------------------------------------------------------------
// One 1024-thread block per (ch,ks) group: stage the FULL 256-row x 64-col
// K-slab ONCE per iter (zero staging redundancy, zero inter-block reuse),
// then 10 waves compute the 10 upper-tri 64x64 tiles from that single
// staging (waves 10-15 stage and idle at MFMA). bf16 LDS slab [256][64],
// 16B-chunk XOR swizzle (chunk^(row&7)): stage writes and frag reads both
// conflict-free. Reg-prefetch one iter ahead, 2 barriers/iter.
// SESSION-BEST configuration (R14/R16: 44.1 us total, reproduced).
// Eleven optimization axes tested and falsified around it (R6-R17):
// occupancy, HBM bytes, L2 bytes, instr count, pipeline depth, barriers,
// bank conflicts, staging engine (incl. global_load_lds), redundancy,
// DRAM run length, active-CU count. gram is pinned ~41 us by an
// aggregate-path latency x concurrency wall on the 344KB-strided row walk;
// every pipe is <=30% in every configuration. A transposing pre-pass
// (176 MB extra round-trip ~= 35 us) cannot pay for itself.
// ---------------------------------------------------------------------------
__global__ __launch_bounds__(1024, 4) void gram_kernel(
    const float* __restrict__ src, const float* __restrict__ tgt,
    float* __restrict__ Gp, int kshift, int kchunk) {
  const int P = 1 << kshift;
  const int g = blockIdx.x;
  const int ch = g >> kshift;
  const int ks = g & (P - 1);
  const int kbase = ks * kchunk;
  const int tid = threadIdx.x;
  const int lane = tid & 63;
  const int wave = tid >> 6;             // 0..15

  __shared__ __attribute__((aligned(16))) ushort S[256 * 64];  // 32 KB bf16 slab

  f32x4 acc[4][4];
#pragma unroll
  for (int m = 0; m < 4; ++m)
#pragma unroll
    for (int n = 0; n < 4; ++n)
      acc[m][n] = (f32x4){0.f, 0.f, 0.f, 0.f};

  // staging geometry: 256 rows x 64 f32 = 4096 16B-chunks; thread handles
  // chunk ids tid, tid+1024, tid+2048, tid+3072 (wave reads 1KB contiguous).
  const float* gptr[4];
  int lw[4];
#pragma unroll
  for (int i = 0; i < 4; ++i) {
    const int id = i * 1024 + tid;
    const int row = id >> 4;             // 0..255
    const int c16 = id & 15;             // f32 chunk within row
    const float* base = (row < 128) ? src + ((size_t)row * NCH + ch) * DIM
                                    : tgt + ((size_t)(row - 128) * NCH + ch) * DIM;
    gptr[i] = base + kbase + c16 * 4;
    const int sch = (c16 >> 1) ^ (row & 7);     // swizzled 16B bf16 chunk
    lw[i] = row * 64 + sch * 8 + (c16 & 1) * 4; // ushort index (8B half-chunk)
  }

  const int ti = g_TI[wave < NTILE ? wave : 0];
  const int tj = g_TJ[wave < NTILE ? wave : 0];

  const int nk = kchunk / BK;  // 8 at P=8

  // prefetch slab 0
  f32x4 v[4];
#pragma unroll
  for (int i = 0; i < 4; ++i) v[i] = *reinterpret_cast<const f32x4*>(gptr[i]);

  for (int it = 0; it < nk; ++it) {
    __syncthreads();  // previous iteration's LDS reads done
    // stage regs -> LDS (cvt_pk, swizzled, conflict-free)
#pragma unroll
    for (int i = 0; i < 4; ++i) {
      uint2 wv;
      wv.x = pack_bf2(v[i].x, v[i].y);
      wv.y = pack_bf2(v[i].z, v[i].w);
      *reinterpret_cast<uint2*>(&S[lw[i]]) = wv;
    }
    // issue next slab's loads; they fly across the MFMA phase
    if (it + 1 < nk) {
      const int ko = (it + 1) * BK;
#pragma unroll
      for (int i = 0; i < 4; ++i)
        v[i] = *reinterpret_cast<const f32x4*>(gptr[i] + ko);
    }
    asm volatile("s_waitcnt lgkmcnt(0)" ::: "memory");  // ds_writes visible
    __builtin_amdgcn_s_barrier();
    asm volatile("" ::: "memory");

    if (wave < NTILE) {
#pragma unroll
      for (int kk = 0; kk < 2; ++kk) {
        const int chunk = kk * 4 + (lane >> 4);  // 16B bf16 chunk 0..7
        bf16x8 a[4], b[4];
#pragma unroll
        for (int m = 0; m < 4; ++m) {
          const int row = ti * 64 + m * 16 + (lane & 15);
          a[m] = *reinterpret_cast<const bf16x8*>(
              &S[row * 64 + ((chunk ^ (row & 7)) << 3)]);
        }
#pragma unroll
        for (int n = 0; n < 4; ++n) {
          const int row = tj * 64 + n * 16 + (lane & 15);
          b[n] = *reinterpret_cast<const bf16x8*>(
              &S[row * 64 + ((chunk ^ (row & 7)) << 3)]);
        }
#pragma unroll
        for (int m = 0; m < 4; ++m)
#pragma unroll
          for (int n = 0; n < 4; ++n)
            acc[m][n] = __builtin_amdgcn_mfma_f32_16x16x32_bf16(a[m], b[n],
                                                                acc[m][n], 0, 0, 0);
      }
    }
  }

  // C/D layout (m89): col = lane&15, row = (lane>>4)*4 + reg.
  if (wave < NTILE) {
    float* gp = Gp + (size_t)(ch * P + ks) * (NROW * NROW);
#pragma unroll
    for (int m = 0; m < 4; ++m)
#pragma unroll
      for (int n = 0; n < 4; ++n) {
        const int grow = ti * 64 + m * 16 + ((lane >> 4) << 2);
        const int gcol = tj * 64 + n * 16 + (lane & 15);
#pragma unroll
        for (int j = 0; j < 4; ++j)
          gp[(size_t)(grow + j) * NROW + gcol] = acc[m][n][j];
      }
  }
}

// ---------------------------------------------------------------------------
__device__ __forceinline__ float block_sum256(float v, float* sm) {
#pragma unroll
  for (int o = 32; o > 0; o >>= 1) v += __shfl_down(v, o, 64);
  const int lane = threadIdx.x & 63;
  const int wv = threadIdx.x >> 6;
  if (lane == 0) sm[wv] = v;
  __syncthreads();
  float r = 0.f;
  if (threadIdx.x == 0) r = sm[0] + sm[1] + sm[2] + sm[3];
  __syncthreads();
  return r;  // valid on thread 0
}

// ---------------------------------------------------------------------------
// Fold K-split partials for one (ch,tile) AND produce tile sum + diag trace.
__global__ __launch_bounds__(256) void foldsum_kernel(
    const f32x4* __restrict__ Gp, f32x4* __restrict__ Gf,
    float* __restrict__ sums, int P) {
  const int t = blockIdx.x;
  const int ch = blockIdx.y;
  const int ti = g_TI[t], tj = g_TJ[t];
  const bool isdiag = (ti == tj);
  const int tid = threadIdx.x;
  float s = 0.f, tr = 0.f;
#pragma unroll
  for (int i = 0; i < 4; ++i) {
    const int idx4 = tid * 4 + i;
    const int rrow = idx4 >> 4;       // 0..63
    const int c4 = idx4 & 15;         // 0..15
    const int base_v = (ti * 64 + rrow) * 64 + tj * 16 + c4;
    f32x4 v = Gp[(size_t)(ch * P) * 16384 + base_v];
    for (int p = 1; p < P; ++p) v += Gp[(size_t)(ch * P + p) * 16384 + base_v];
    Gf[(size_t)ch * 16384 + base_v] = v;
    s += (v.x + v.y) + (v.z + v.w);
    if (isdiag) {
      const int cb = c4 * 4;
#pragma unroll
      for (int e = 0; e < 4; ++e)
        if (cb + e == rrow) tr += v[e];
    }
  }
  __shared__ float sm[4];
  float sG = block_sum256(s, sm);
  float sT = block_sum256(tr, sm);
  if (tid == 0) {
    sums[ch * 20 + t] = sG;
    if (isdiag) sums[ch * 20 + 10 + ti] = sT;
  }
}

// ---------------------------------------------------------------------------
// per (tile, ch): w * sign * sum over tile of sum_a exp(-L2/(bw*2^a)).
__global__ __launch_bounds__(256) void mmd_kernel(const float* __restrict__ Gf,
                                                  const float* __restrict__ sums,
                                                  float* __restrict__ partial) {
  const int t = blockIdx.x;
  const int ch = blockIdx.y;
  const int ti = g_TI[t], tj = g_TJ[t];
  const int tid = threadIdx.x;
  const float* gg = Gf + (size_t)ch * (NROW * NROW);

  const float* sc = sums + ch * 20;
  float sumG = 0.f;
#pragma unroll
  for (int k = 0; k < NTILE; ++k)
    sumG += (g_TI[k] == g_TJ[k] ? 1.f : 2.f) * sc[k];
  const float trace = (sc[10] + sc[11]) + (sc[12] + sc[13]);
  const float sumL2 = 2.f * NROW * trace - 2.f * sumG;
  const float bw = sumL2 / (float)(NROW * NROW - NROW) * 0.25f;
  float inv[5];
#pragma unroll
  for (int a = 0; a < 5; ++a) inv[a] = -1.f / (bw * (float)(1 << a));

  __shared__ float dA[64], dB[64];
  if (tid < 64) dA[tid] = gg[(size_t)(ti * 64 + tid) * (NROW + 1)];
  else if (tid < 128) dB[tid - 64] = gg[(size_t)(tj * 64 + (tid - 64)) * (NROW + 1)];
  __syncthreads();

  const int col = tid & 63;
  const int qq = tid >> 6;
  const float dj = dB[col];
  float acc = 0.f;
#pragma unroll 4
  for (int it = 0; it < 16; ++it) {
    const int r = it * 4 + qq;
    const float L2 = dA[r] + dj - 2.f * gg[(size_t)(ti * 64 + r) * NROW + tj * 64 + col];
    float kv = 0.f;
#pragma unroll
    for (int a = 0; a < 5; ++a) kv += __expf(L2 * inv[a]);
    acc += kv;
  }
  __shared__ float sm[4];
  float tot = block_sum256(acc, sm);
  if (tid == 0) {
    float wgt = (ti == tj) ? 1.f : 2.f;                  // off-diag mirror
    float sgn = ((ti >= 2) == (tj >= 2)) ? 1.f : -1.f;   // XX/YY + , XY/YX -
    partial[ch * NTILE + t] = tot * wgt * sgn;
  }
}

__global__ __launch_bounds__(256) void final_kernel(const float* __restrict__ partial,
                                                    float* __restrict__ out) {
  const int tid = threadIdx.x;
  float v = (tid < NCH * NTILE) ? partial[tid] : 0.f;
  __shared__ float sm[4];
  float tot = block_sum256(v, sm);
  if (tid == 0) out[0] = tot * (1.f / (NCH * 128.f * 128.f));
}

// ---------------------------------------------------------------------------
extern "C" void kernel_launch(void* const* d_in, const int* in_sizes, int n_in,
                              void* d_out, int out_size, void* d_ws, size_t ws_size,
                              hipStream_t stream) {
  const float* src = (const float*)d_in[0];
  const float* tgt = (const float*)d_in[1];
  float* out = (float*)d_out;
  const size_t GSZ = (size_t)NROW * NROW;  // 65536

  // P capped at 8 (P=16 blew up foldsum R10; P=12 regressed total R17).
  int kshift = 0;
  if (ws_size >= (NCH * 9 * GSZ + 512) * sizeof(float)) kshift = 3;
  else if (ws_size >= (NCH * 5 * GSZ + 512) * sizeof(float)) kshift = 2;
  else if (ws_size >= (NCH * 3 * GSZ + 512) * sizeof(float)) kshift = 1;
  const int P = 1 << kshift;

  float* Gp = (float*)d_ws;
  float* Gf = (P > 1) ? Gp + (size_t)NCH * P * GSZ : Gp;  // P==1: alias
  float* sums = Gf + (size_t)NCH * GSZ;                   // NCH*20
  float* partial = sums + NCH * 20;                       // NCH*10

  gram_kernel<<<dim3(NCH * P), 1024, 0, stream>>>(src, tgt, Gp, kshift,
                                                  DIM >> kshift);
  foldsum_kernel<<<dim3(NTILE, NCH), 256, 0, stream>>>((const f32x4*)Gp,
                                                       (f32x4*)Gf, sums, P);
  mmd_kernel<<<dim3(NTILE, NCH), 256, 0, stream>>>(Gf, sums, partial);
  final_kernel<<<1, 256, 0, stream>>>(partial, out);
}